// Round 3
// baseline (349.247 us; speedup 1.0000x reference)
//
#include <hip/hip_runtime.h>

#define NM    4096
#define NPTS  131072
#define CAP   128

typedef _Float16 h2 __attribute__((ext_vector_type(2)));

#if __has_builtin(__builtin_amdgcn_fdot2)
#define FDOT2(a, b, c) __builtin_amdgcn_fdot2((a), (b), (c), false)
#else
static __device__ inline float FDOT2(h2 a, h2 b, float c) {
    return c + (float)a.x * (float)b.x + (float)a.y * (float)b.y;
}
#endif

static __device__ inline h2 pk(float a, float b) {
    return __builtin_bit_cast(h2, __builtin_amdgcn_cvt_pkrtz(a, b));
}

__global__ __launch_bounds__(256) void k_bucket(const float* __restrict__ pts,
                                                int* __restrict__ count,
                                                int* __restrict__ plist) {
    int n = blockIdx.x * 256 + threadIdx.x;
    if (n >= NPTS) return;
    float x = pts[3 * n + 0], y = pts[3 * n + 1], z = pts[3 * n + 2];
    int ix = (int)fminf(fmaxf(x * 16.f, 0.f), 15.f);
    int iy = (int)fminf(fmaxf(y * 16.f, 0.f), 15.f);
    int iz = (int)fminf(fmaxf(z * 16.f, 0.f), 15.f);
    int v = (ix << 8) | (iy << 4) | iz;
    int pos = atomicAdd(&count[v], 1);
    if (pos < CAP) plist[v * CAP + pos] = n;
}

__global__ __launch_bounds__(128) void k_mlp(
    const float* __restrict__ pts, const float* __restrict__ vds,
    const float* __restrict__ w0g, const float* __restrict__ b0g,
    const float* __restrict__ w1g, const float* __restrict__ b1g,
    const float* __restrict__ fwg, const float* __restrict__ fbg,
    const float* __restrict__ swg, const float* __restrict__ sbg,
    const float* __restrict__ vwg, const float* __restrict__ vbg,
    const float* __restrict__ rwg, const float* __restrict__ rbg,
    const int* __restrict__ count, const int* __restrict__ plist,
    float* __restrict__ out) {
    // f16-pair weight staging: rows padded to 32 half2 (64 dims)
    __shared__ __align__(16) h2 sW0[32 * 32];   // 4 KB  (63 -> 32 h2)
    __shared__ __align__(16) h2 sVW[32 * 32];   // 4 KB  (59 -> 32 h2)
    __shared__ __align__(16) h2 sW1[32 * 16];   // 2 KB
    __shared__ __align__(16) h2 sFW[32 * 16];   // 2 KB
    __shared__ __align__(16) h2 sSW[16];
    __shared__ __align__(16) h2 sRW[3 * 16];
    __shared__ float sB0[32], sB1[32], sFB[32], sVB[32], sRB[3], sSB[1];

    const int v = blockIdx.x;
    const int t = threadIdx.x;
    const int c = min(count[v], CAP);
    if (c == 0) return;

    // ---- stage weights (128 threads) ----
    {
        const float* w0p = w0g + (size_t)v * 2016;
        #pragma unroll
        for (int i = t; i < 1024; i += 128) {
            int r = i >> 5, j = i & 31;
            float f0 = w0p[r * 63 + 2 * j];
            float f1 = (2 * j + 1 < 63) ? w0p[r * 63 + 2 * j + 1] : 0.f;
            sW0[i] = pk(f0, f1);
        }
        const float* vwp = vwg + (size_t)v * 1888;
        #pragma unroll
        for (int i = t; i < 1024; i += 128) {
            int r = i >> 5, j = i & 31;
            int d0 = 2 * j, d1 = 2 * j + 1;
            float f0 = (d0 < 59) ? vwp[r * 59 + d0] : 0.f;
            float f1 = (d1 < 59) ? vwp[r * 59 + d1] : 0.f;
            sVW[i] = pk(f0, f1);
        }
        const float2* w1p = (const float2*)(w1g + (size_t)v * 1024);
        #pragma unroll
        for (int i = t; i < 512; i += 128) { float2 f = w1p[i]; sW1[i] = pk(f.x, f.y); }
        const float2* fwp = (const float2*)(fwg + (size_t)v * 1024);
        #pragma unroll
        for (int i = t; i < 512; i += 128) { float2 f = fwp[i]; sFW[i] = pk(f.x, f.y); }
        if (t < 16) { float2 f = ((const float2*)(swg + (size_t)v * 32))[t]; sSW[t] = pk(f.x, f.y); }
        if (t < 48) { float2 f = ((const float2*)(rwg + (size_t)v * 96))[t]; sRW[t] = pk(f.x, f.y); }
        if (t < 32) {
            sB0[t] = b0g[v * 32 + t];
            sB1[t] = b1g[v * 32 + t];
            sFB[t] = fbg[v * 32 + t];
            sVB[t] = vbg[v * 32 + t];
        }
        if (t < 3) sRB[t] = rbg[v * 3 + t];
        if (t == 3) sSB[0] = sbg[v];
    }
    __syncthreads();

    const int wave = t >> 6;         // 2 waves: wave w starts at chunk w
    const int lane = t & 63;
    const int half = lane & 1;       // 2 lanes per point
    const int rb16 = half << 4;      // this lane's 16 output rows
    const int slotIn = lane >> 1;

    for (int base = wave * 32; base < c; base += 64) {
        const int slot = base + slotIn;
        const bool active = slot < c;
        const int n = plist[v * CAP + min(slot, c - 1)];

        const float px = pts[3 * n], py = pts[3 * n + 1], pz = pts[3 * n + 2];
        const int ray = n >> 7;
        const float dx = vds[3 * ray], dy = vds[3 * ray + 1], dz = vds[3 * ray + 2];

        // ---- xyz encoding -> 63 dims (+pad) packed as 32 h2 ----
        float e[64];
        e[0] = px; e[1] = py; e[2] = pz;
        {
            float f = 1.f;
            #pragma unroll
            for (int k = 0; k < 10; k++) {
                e[3 + 6 * k + 0] = __sinf(px * f);
                e[3 + 6 * k + 1] = __sinf(py * f);
                e[3 + 6 * k + 2] = __sinf(pz * f);
                e[3 + 6 * k + 3] = __cosf(px * f);
                e[3 + 6 * k + 4] = __cosf(py * f);
                e[3 + 6 * k + 5] = __cosf(pz * f);
                f *= 2.f;
            }
        }
        e[63] = 0.f;
        h2 eph[32];
        #pragma unroll
        for (int j = 0; j < 32; j++) eph[j] = pk(e[2 * j], e[2 * j + 1]);

        // ---- layer 0 ----
        float h[16];
        #pragma unroll
        for (int o = 0; o < 16; o++) {
            const h2* wr = &sW0[(rb16 + o) << 5];
            float a0 = sB0[rb16 + o], a1 = 0.f;
            #pragma unroll
            for (int j = 0; j < 32; j += 2) {
                a0 = FDOT2(wr[j], eph[j], a0);
                a1 = FDOT2(wr[j + 1], eph[j + 1], a1);
            }
            h[o] = fmaxf(a0 + a1, 0.f);
        }
        // exchange -> full 32 activations as 16 h2
        h2 hh[16];
        {
            float ho[16];
            #pragma unroll
            for (int j = 0; j < 16; j++) ho[j] = __shfl_xor(h[j], 1, 64);
            #pragma unroll
            for (int j = 0; j < 8; j++) {
                hh[j]     = pk(half ? ho[2 * j] : h[2 * j],  half ? ho[2 * j + 1] : h[2 * j + 1]);
                hh[8 + j] = pk(half ? h[2 * j] : ho[2 * j],  half ? h[2 * j + 1] : ho[2 * j + 1]);
            }
        }

        // ---- layer 1 ----
        float g[16];
        #pragma unroll
        for (int o = 0; o < 16; o++) {
            const h2* wr = &sW1[(rb16 + o) << 4];
            float a0 = sB1[rb16 + o], a1 = 0.f;
            #pragma unroll
            for (int j = 0; j < 16; j += 2) {
                a0 = FDOT2(wr[j], hh[j], a0);
                a1 = FDOT2(wr[j + 1], hh[j + 1], a1);
            }
            g[o] = fmaxf(a0 + a1, 0.f);
        }
        h2 gh[16];
        {
            float go[16];
            #pragma unroll
            for (int j = 0; j < 16; j++) go[j] = __shfl_xor(g[j], 1, 64);
            #pragma unroll
            for (int j = 0; j < 8; j++) {
                gh[j]     = pk(half ? go[2 * j] : g[2 * j],  half ? go[2 * j + 1] : g[2 * j + 1]);
                gh[8 + j] = pk(half ? g[2 * j] : go[2 * j],  half ? g[2 * j + 1] : go[2 * j + 1]);
            }
        }

        // ---- sigma ----
        float sg;
        {
            float a0 = sSB[0], a1 = 0.f;
            #pragma unroll
            for (int j = 0; j < 16; j += 2) {
                a0 = FDOT2(sSW[j], gh[j], a0);
                a1 = FDOT2(sSW[j + 1], gh[j + 1], a1);
            }
            sg = a0 + a1;
        }

        // ---- feature layer (no relu) ----
        float ft[16];
        #pragma unroll
        for (int o = 0; o < 16; o++) {
            const h2* wr = &sFW[(rb16 + o) << 4];
            float a0 = sFB[rb16 + o], a1 = 0.f;
            #pragma unroll
            for (int j = 0; j < 16; j += 2) {
                a0 = FDOT2(wr[j], gh[j], a0);
                a1 = FDOT2(wr[j + 1], gh[j + 1], a1);
            }
            ft[o] = a0 + a1;
        }

        // ---- view input: feat(32) + dir encoding(27) + pad -> 32 h2 ----
        h2 hv[32];
        {
            float fo[16];
            #pragma unroll
            for (int j = 0; j < 16; j++) fo[j] = __shfl_xor(ft[j], 1, 64);
            #pragma unroll
            for (int j = 0; j < 8; j++) {
                hv[j]     = pk(half ? fo[2 * j] : ft[2 * j],  half ? fo[2 * j + 1] : ft[2 * j + 1]);
                hv[8 + j] = pk(half ? ft[2 * j] : fo[2 * j],  half ? ft[2 * j + 1] : fo[2 * j + 1]);
            }
            float dv[32];
            dv[0] = dx; dv[1] = dy; dv[2] = dz;
            float f = 1.f;
            #pragma unroll
            for (int k = 0; k < 4; k++) {
                dv[3 + 6 * k + 0] = __sinf(dx * f);
                dv[3 + 6 * k + 1] = __sinf(dy * f);
                dv[3 + 6 * k + 2] = __sinf(dz * f);
                dv[3 + 6 * k + 3] = __cosf(dx * f);
                dv[3 + 6 * k + 4] = __cosf(dy * f);
                dv[3 + 6 * k + 5] = __cosf(dz * f);
                f *= 2.f;
            }
            #pragma unroll
            for (int j = 27; j < 32; j++) dv[j] = 0.f;
            #pragma unroll
            for (int j = 0; j < 16; j++) hv[16 + j] = pk(dv[2 * j], dv[2 * j + 1]);
        }

        // ---- view layer ----
        float h3[16];
        #pragma unroll
        for (int o = 0; o < 16; o++) {
            const h2* wr = &sVW[(rb16 + o) << 5];
            float a0 = sVB[rb16 + o], a1 = 0.f;
            #pragma unroll
            for (int j = 0; j < 32; j += 2) {
                a0 = FDOT2(wr[j], hv[j], a0);
                a1 = FDOT2(wr[j + 1], hv[j + 1], a1);
            }
            h3[o] = fmaxf(a0 + a1, 0.f);
        }
        h2 h3h[16];
        {
            float ho[16];
            #pragma unroll
            for (int j = 0; j < 16; j++) ho[j] = __shfl_xor(h3[j], 1, 64);
            #pragma unroll
            for (int j = 0; j < 8; j++) {
                h3h[j]     = pk(half ? ho[2 * j] : h3[2 * j],  half ? ho[2 * j + 1] : h3[2 * j + 1]);
                h3h[8 + j] = pk(half ? h3[2 * j] : ho[2 * j],  half ? h3[2 * j + 1] : ho[2 * j + 1]);
            }
        }

        // ---- rgb ----
        float r0 = sRB[0], r1 = sRB[1], r2 = sRB[2];
        {
            float b0 = 0.f, b1 = 0.f, b2 = 0.f;
            #pragma unroll
            for (int j = 0; j < 16; j += 2) {
                r0 = FDOT2(sRW[j], h3h[j], r0);       b0 = FDOT2(sRW[j + 1], h3h[j + 1], b0);
                r1 = FDOT2(sRW[16 + j], h3h[j], r1);  b1 = FDOT2(sRW[16 + j + 1], h3h[j + 1], b1);
                r2 = FDOT2(sRW[32 + j], h3h[j], r2);  b2 = FDOT2(sRW[32 + j + 1], h3h[j + 1], b2);
            }
            r0 += b0; r1 += b1; r2 += b2;
        }

        if (active && half == 0) {
            out[3 * n + 0] = r0;
            out[3 * n + 1] = r1;
            out[3 * n + 2] = r2;
            out[3 * NPTS + n] = sg;
        }
    }
}

extern "C" void kernel_launch(void* const* d_in, const int* in_sizes, int n_in,
                              void* d_out, int out_size, void* d_ws, size_t ws_size,
                              hipStream_t stream) {
    const float* pts = (const float*)d_in[0];
    const float* vds = (const float*)d_in[1];
    const float* w0  = (const float*)d_in[2];
    const float* b0  = (const float*)d_in[3];
    const float* w1  = (const float*)d_in[4];
    const float* b1  = (const float*)d_in[5];
    const float* fw  = (const float*)d_in[6];
    const float* fb  = (const float*)d_in[7];
    const float* sw  = (const float*)d_in[8];
    const float* sb  = (const float*)d_in[9];
    const float* vw  = (const float*)d_in[10];
    const float* vb  = (const float*)d_in[11];
    const float* rw  = (const float*)d_in[12];
    const float* rb  = (const float*)d_in[13];
    float* out = (float*)d_out;

    int* count = (int*)d_ws;
    int* plist = (int*)((char*)d_ws + NM * sizeof(int));

    (void)hipMemsetAsync(count, 0, NM * sizeof(int), stream);
    k_bucket<<<NPTS / 256, 256, 0, stream>>>(pts, count, plist);
    k_mlp<<<NM, 128, 0, stream>>>(pts, vds, w0, b0, w1, b1, fw, fb, sw, sb,
                                  vw, vb, rw, rb, count, plist, out);
}

// Round 4
// 333.864 us; speedup vs baseline: 1.0461x; 1.0461x over previous
//
#include <hip/hip_runtime.h>

#define NM    4096
#define NPTS  131072
#define CAP   128

typedef _Float16 h2 __attribute__((ext_vector_type(2)));

#if __has_builtin(__builtin_amdgcn_fdot2)
#define FDOT2(a, b, c) __builtin_amdgcn_fdot2((a), (b), (c), false)
#else
static __device__ inline float FDOT2(h2 a, h2 b, float c) {
    return c + (float)a.x * (float)b.x + (float)a.y * (float)b.y;
}
#endif

static __device__ inline h2 pk(float a, float b) {
    return __builtin_bit_cast(h2, __builtin_amdgcn_cvt_pkrtz(a, b));
}

// Skewed LDS layout: 2 half-blocks of 16 rows, +4 h2 (16B) skew between
// halves so the wave's two broadcast rows hit different banks.
#define W0_HALF 516   // 16 rows * 32 h2 + 4
#define W1_HALF 260   // 16 rows * 16 h2 + 4

__global__ __launch_bounds__(256) void k_bucket(const float* __restrict__ pts,
                                                int* __restrict__ count,
                                                int* __restrict__ plist) {
    int n = blockIdx.x * 256 + threadIdx.x;
    if (n >= NPTS) return;
    float x = pts[3 * n + 0], y = pts[3 * n + 1], z = pts[3 * n + 2];
    int ix = (int)fminf(fmaxf(x * 16.f, 0.f), 15.f);
    int iy = (int)fminf(fmaxf(y * 16.f, 0.f), 15.f);
    int iz = (int)fminf(fmaxf(z * 16.f, 0.f), 15.f);
    int v = (ix << 8) | (iy << 4) | iz;
    int pos = atomicAdd(&count[v], 1);
    if (pos < CAP) plist[v * CAP + pos] = n;
}

__global__ __launch_bounds__(64, 4) void k_mlp(
    const float* __restrict__ pts, const float* __restrict__ vds,
    const float* __restrict__ w0g, const float* __restrict__ b0g,
    const float* __restrict__ w1g, const float* __restrict__ b1g,
    const float* __restrict__ fwg, const float* __restrict__ fbg,
    const float* __restrict__ swg, const float* __restrict__ sbg,
    const float* __restrict__ vwg, const float* __restrict__ vbg,
    const float* __restrict__ rwg, const float* __restrict__ rbg,
    const int* __restrict__ count, const int* __restrict__ plist,
    float* __restrict__ out) {
    __shared__ __align__(16) h2 sW0[2 * W0_HALF];
    __shared__ __align__(16) h2 sVW[2 * W0_HALF];
    __shared__ __align__(16) h2 sW1[2 * W1_HALF];
    __shared__ __align__(16) h2 sFW[2 * W1_HALF];
    __shared__ __align__(16) h2 sSW[16];
    __shared__ __align__(16) h2 sRW[48];
    __shared__ float sB0[32], sB1[32], sFB[32], sVB[32], sRB[3], sSB[1];

    const int v = blockIdx.x;
    const int t = threadIdx.x;
    const int c = min(count[v], CAP);
    if (c == 0) return;

    // ---- stage weights (64 threads) ----
    {
        const float* w0p = w0g + (size_t)v * 2016;   // rows of 63
        #pragma unroll
        for (int i = t; i < 1024; i += 64) {
            int r = i >> 5, j = i & 31;
            const float* rp = w0p + r * 63;
            float f0 = rp[2 * j];                     // 2j <= 62: valid
            float f1 = (j < 31) ? rp[2 * j + 1] : 0.f;
            sW0[(r >> 4) * W0_HALF + (r & 15) * 32 + j] = pk(f0, f1);
        }
        const float* vwp = vwg + (size_t)v * 1888;   // rows of 59
        #pragma unroll
        for (int i = t; i < 1024; i += 64) {
            int r = i >> 5, j = i & 31;
            const float* rp = vwp + r * 59;
            float f0 = (j < 30) ? rp[2 * j] : 0.f;
            float f1 = (j < 29) ? rp[2 * j + 1] : 0.f;
            if (j == 29) f0 = rp[58];
            sVW[(r >> 4) * W0_HALF + (r & 15) * 32 + j] = pk(f0, f1);
        }
        const float4* w1p = (const float4*)(w1g + (size_t)v * 1024);
        #pragma unroll
        for (int k = t; k < 256; k += 64) {
            float4 f = w1p[k];
            int r = k >> 3, jj = (k & 7) * 2;
            h2* dst = &sW1[(r >> 4) * W1_HALF + (r & 15) * 16 + jj];
            dst[0] = pk(f.x, f.y); dst[1] = pk(f.z, f.w);
        }
        const float4* fwp = (const float4*)(fwg + (size_t)v * 1024);
        #pragma unroll
        for (int k = t; k < 256; k += 64) {
            float4 f = fwp[k];
            int r = k >> 3, jj = (k & 7) * 2;
            h2* dst = &sFW[(r >> 4) * W1_HALF + (r & 15) * 16 + jj];
            dst[0] = pk(f.x, f.y); dst[1] = pk(f.z, f.w);
        }
        if (t < 8) {
            float4 f = ((const float4*)(swg + (size_t)v * 32))[t];
            sSW[2 * t] = pk(f.x, f.y); sSW[2 * t + 1] = pk(f.z, f.w);
        }
        if (t < 24) {
            float4 f = ((const float4*)(rwg + (size_t)v * 96))[t];
            h2* dst = &sRW[(t >> 3) * 16 + (t & 7) * 2];
            dst[0] = pk(f.x, f.y); dst[1] = pk(f.z, f.w);
        }
        if (t < 32) {
            sB0[t] = b0g[v * 32 + t];
            sB1[t] = b1g[v * 32 + t];
            sFB[t] = fbg[v * 32 + t];
            sVB[t] = vbg[v * 32 + t];
        }
        if (t < 3) sRB[t] = rbg[v * 3 + t];
        if (t == 3) sSB[0] = sbg[v];
    }
    __syncthreads();

    const int half = t & 1;          // 2 lanes per point: 16 rows each
    const int rb16 = half << 4;

    for (int base = 0; base < c; base += 32) {
        const int slot = base + (t >> 1);
        const bool active = slot < c;
        const int n = plist[v * CAP + min(slot, c - 1)];

        const float px = pts[3 * n], py = pts[3 * n + 1], pz = pts[3 * n + 2];
        const int ray = n >> 7;
        const float dx = vds[3 * ray], dy = vds[3 * ray + 1], dz = vds[3 * ray + 2];

        // ---- xyz encoding packed directly into h2 (carry chain, no f32 array) ----
        h2 eph[32];
        eph[0] = pk(px, py);
        {
            float carry = pz, f = 1.f;
            #pragma unroll
            for (int k = 0; k < 10; k++) {
                float s0 = __sinf(px * f), s1 = __sinf(py * f), s2 = __sinf(pz * f);
                float c0 = __cosf(px * f), c1 = __cosf(py * f), c2 = __cosf(pz * f);
                eph[1 + 3 * k] = pk(carry, s0);
                eph[2 + 3 * k] = pk(s1, s2);
                eph[3 + 3 * k] = pk(c0, c1);
                carry = c2;
                f *= 2.f;
            }
            eph[31] = pk(carry, 0.f);
        }

        // ---- layer 0 ----
        float h[16];
        #pragma unroll
        for (int o = 0; o < 16; o++) {
            const h2* wr = &sW0[half * W0_HALF + o * 32];
            float a0 = sB0[rb16 + o], a1 = 0.f;
            #pragma unroll
            for (int j = 0; j < 32; j += 2) {
                a0 = FDOT2(wr[j], eph[j], a0);
                a1 = FDOT2(wr[j + 1], eph[j + 1], a1);
            }
            h[o] = fmaxf(a0 + a1, 0.f);
        }
        h2 hh[16];
        {
            float ho[16];
            #pragma unroll
            for (int j = 0; j < 16; j++) ho[j] = __shfl_xor(h[j], 1, 64);
            #pragma unroll
            for (int j = 0; j < 8; j++) {
                hh[j]     = pk(half ? ho[2 * j] : h[2 * j],  half ? ho[2 * j + 1] : h[2 * j + 1]);
                hh[8 + j] = pk(half ? h[2 * j] : ho[2 * j],  half ? h[2 * j + 1] : ho[2 * j + 1]);
            }
        }

        // ---- layer 1 ----
        float g[16];
        #pragma unroll
        for (int o = 0; o < 16; o++) {
            const h2* wr = &sW1[half * W1_HALF + o * 16];
            float a0 = sB1[rb16 + o], a1 = 0.f;
            #pragma unroll
            for (int j = 0; j < 16; j += 2) {
                a0 = FDOT2(wr[j], hh[j], a0);
                a1 = FDOT2(wr[j + 1], hh[j + 1], a1);
            }
            g[o] = fmaxf(a0 + a1, 0.f);
        }
        h2 gh[16];
        {
            float go[16];
            #pragma unroll
            for (int j = 0; j < 16; j++) go[j] = __shfl_xor(g[j], 1, 64);
            #pragma unroll
            for (int j = 0; j < 8; j++) {
                gh[j]     = pk(half ? go[2 * j] : g[2 * j],  half ? go[2 * j + 1] : g[2 * j + 1]);
                gh[8 + j] = pk(half ? g[2 * j] : go[2 * j],  half ? g[2 * j + 1] : go[2 * j + 1]);
            }
        }

        // ---- sigma (both pair lanes compute it; half==0 stores) ----
        float sg;
        {
            float a0 = sSB[0], a1 = 0.f;
            #pragma unroll
            for (int j = 0; j < 16; j += 2) {
                a0 = FDOT2(sSW[j], gh[j], a0);
                a1 = FDOT2(sSW[j + 1], gh[j + 1], a1);
            }
            sg = a0 + a1;
        }

        // ---- feature layer (no relu) ----
        float ft[16];
        #pragma unroll
        for (int o = 0; o < 16; o++) {
            const h2* wr = &sFW[half * W1_HALF + o * 16];
            float a0 = sFB[rb16 + o], a1 = 0.f;
            #pragma unroll
            for (int j = 0; j < 16; j += 2) {
                a0 = FDOT2(wr[j], gh[j], a0);
                a1 = FDOT2(wr[j + 1], gh[j + 1], a1);
            }
            ft[o] = a0 + a1;
        }

        // ---- view input: feat(32) + dir encoding(27) + pad ----
        h2 hv[32];
        {
            float fo[16];
            #pragma unroll
            for (int j = 0; j < 16; j++) fo[j] = __shfl_xor(ft[j], 1, 64);
            #pragma unroll
            for (int j = 0; j < 8; j++) {
                hv[j]     = pk(half ? fo[2 * j] : ft[2 * j],  half ? fo[2 * j + 1] : ft[2 * j + 1]);
                hv[8 + j] = pk(half ? ft[2 * j] : fo[2 * j],  half ? ft[2 * j + 1] : fo[2 * j + 1]);
            }
            hv[16] = pk(dx, dy);
            float carry = dz, f = 1.f;
            #pragma unroll
            for (int k = 0; k < 4; k++) {
                float s0 = __sinf(dx * f), s1 = __sinf(dy * f), s2 = __sinf(dz * f);
                float c0 = __cosf(dx * f), c1 = __cosf(dy * f), c2 = __cosf(dz * f);
                hv[17 + 3 * k] = pk(carry, s0);
                hv[18 + 3 * k] = pk(s1, s2);
                hv[19 + 3 * k] = pk(c0, c1);
                carry = c2;
                f *= 2.f;
            }
            hv[29] = pk(carry, 0.f);
            hv[30] = pk(0.f, 0.f);
            hv[31] = pk(0.f, 0.f);
        }

        // ---- view layer ----
        float h3[16];
        #pragma unroll
        for (int o = 0; o < 16; o++) {
            const h2* wr = &sVW[half * W0_HALF + o * 32];
            float a0 = sVB[rb16 + o], a1 = 0.f;
            #pragma unroll
            for (int j = 0; j < 32; j += 2) {
                a0 = FDOT2(wr[j], hv[j], a0);
                a1 = FDOT2(wr[j + 1], hv[j + 1], a1);
            }
            h3[o] = fmaxf(a0 + a1, 0.f);
        }
        h2 h3h[16];
        {
            float ho[16];
            #pragma unroll
            for (int j = 0; j < 16; j++) ho[j] = __shfl_xor(h3[j], 1, 64);
            #pragma unroll
            for (int j = 0; j < 8; j++) {
                h3h[j]     = pk(half ? ho[2 * j] : h3[2 * j],  half ? ho[2 * j + 1] : h3[2 * j + 1]);
                h3h[8 + j] = pk(half ? h3[2 * j] : ho[2 * j],  half ? h3[2 * j + 1] : ho[2 * j + 1]);
            }
        }

        // ---- rgb ----
        float r0 = sRB[0], r1 = sRB[1], r2 = sRB[2];
        {
            float b0 = 0.f, b1 = 0.f, b2 = 0.f;
            #pragma unroll
            for (int j = 0; j < 16; j += 2) {
                r0 = FDOT2(sRW[j], h3h[j], r0);       b0 = FDOT2(sRW[j + 1], h3h[j + 1], b0);
                r1 = FDOT2(sRW[16 + j], h3h[j], r1);  b1 = FDOT2(sRW[16 + j + 1], h3h[j + 1], b1);
                r2 = FDOT2(sRW[32 + j], h3h[j], r2);  b2 = FDOT2(sRW[32 + j + 1], h3h[j + 1], b2);
            }
            r0 += b0; r1 += b1; r2 += b2;
        }

        if (active && half == 0) {
            out[3 * n + 0] = r0;
            out[3 * n + 1] = r1;
            out[3 * n + 2] = r2;
            out[3 * NPTS + n] = sg;
        }
    }
}

extern "C" void kernel_launch(void* const* d_in, const int* in_sizes, int n_in,
                              void* d_out, int out_size, void* d_ws, size_t ws_size,
                              hipStream_t stream) {
    const float* pts = (const float*)d_in[0];
    const float* vds = (const float*)d_in[1];
    const float* w0  = (const float*)d_in[2];
    const float* b0  = (const float*)d_in[3];
    const float* w1  = (const float*)d_in[4];
    const float* b1  = (const float*)d_in[5];
    const float* fw  = (const float*)d_in[6];
    const float* fb  = (const float*)d_in[7];
    const float* sw  = (const float*)d_in[8];
    const float* sb  = (const float*)d_in[9];
    const float* vw  = (const float*)d_in[10];
    const float* vb  = (const float*)d_in[11];
    const float* rw  = (const float*)d_in[12];
    const float* rb  = (const float*)d_in[13];
    float* out = (float*)d_out;

    int* count = (int*)d_ws;
    int* plist = (int*)((char*)d_ws + NM * sizeof(int));

    (void)hipMemsetAsync(count, 0, NM * sizeof(int), stream);
    k_bucket<<<NPTS / 256, 256, 0, stream>>>(pts, count, plist);
    k_mlp<<<NM, 64, 0, stream>>>(pts, vds, w0, b0, w1, b1, fw, fb, sw, sb,
                                 vw, vb, rw, rb, count, plist, out);
}

// Round 5
// 269.265 us; speedup vs baseline: 1.2970x; 1.2399x over previous
//
#include <hip/hip_runtime.h>

#define NM    4096
#define NPTS  131072
#define CAP   128

typedef _Float16 h2 __attribute__((ext_vector_type(2)));

#if __has_builtin(__builtin_amdgcn_fdot2)
#define FDOT2(a, b, c) __builtin_amdgcn_fdot2((a), (b), (c), false)
#else
static __device__ inline float FDOT2(h2 a, h2 b, float c) {
    return c + (float)a.x * (float)b.x + (float)a.y * (float)b.y;
}
#endif

#if __has_builtin(__builtin_amdgcn_global_load_lds)
#define USE_DMA 1
#else
#define USE_DMA 0
#endif

static __device__ inline h2 pk(float a, float b) {
    return __builtin_bit_cast(h2, __builtin_amdgcn_cvt_pkrtz(a, b));
}

// Skewed fp16 LDS layout: 2 half-blocks of 16 rows, +4 h2 (16B) skew so the
// wave's two broadcast rows hit different banks (verified: conflicts -> 0).
#define W0_HALF 516   // 16 rows * 32 h2 + 4
#define W1_HALF 260   // 16 rows * 16 h2 + 4

// fp32 packed DMA scratch offsets (floats). Byte-identical to global layout.
#define SCR_W0 0      // 2016
#define SCR_VW 2016   // 1888
#define SCR_W1 3904   // 1024
#define SCR_FW 4928   // 1024
#define SCR_SW 5952   // 32
#define SCR_RW 5984   // 96
#define SCR_TOT 6080

#if USE_DMA
static __device__ inline void dma16(const float* g, const float* l) {
    __builtin_amdgcn_global_load_lds(
        (const __attribute__((address_space(1))) void*)g,
        (__attribute__((address_space(3))) void*)l, 16, 0, 0);
}
#endif

__global__ __launch_bounds__(256) void k_bucket(const float* __restrict__ pts,
                                                int* __restrict__ count,
                                                int* __restrict__ plist) {
    int n = blockIdx.x * 256 + threadIdx.x;
    if (n >= NPTS) return;
    float x = pts[3 * n + 0], y = pts[3 * n + 1], z = pts[3 * n + 2];
    int ix = (int)fminf(fmaxf(x * 16.f, 0.f), 15.f);
    int iy = (int)fminf(fmaxf(y * 16.f, 0.f), 15.f);
    int iz = (int)fminf(fmaxf(z * 16.f, 0.f), 15.f);
    int v = (ix << 8) | (iy << 4) | iz;
    int pos = atomicAdd(&count[v], 1);
    if (pos < CAP) plist[v * CAP + pos] = n;
}

__global__ __launch_bounds__(64) void k_mlp(
    const float* __restrict__ pts, const float* __restrict__ vds,
    const float* __restrict__ w0g, const float* __restrict__ b0g,
    const float* __restrict__ w1g, const float* __restrict__ b1g,
    const float* __restrict__ fwg, const float* __restrict__ fbg,
    const float* __restrict__ swg, const float* __restrict__ sbg,
    const float* __restrict__ vwg, const float* __restrict__ vbg,
    const float* __restrict__ rwg, const float* __restrict__ rbg,
    const int* __restrict__ count, const int* __restrict__ plist,
    float* __restrict__ out) {
    __shared__ __align__(16) float scr[SCR_TOT];   // packed fp32 DMA target
    __shared__ __align__(16) h2 sW0[2 * W0_HALF];
    __shared__ __align__(16) h2 sVW[2 * W0_HALF];
    __shared__ __align__(16) h2 sW1[2 * W1_HALF];
    __shared__ __align__(16) h2 sFW[2 * W1_HALF];
    __shared__ __align__(16) h2 sSW[16];
    __shared__ __align__(16) h2 sRW[48];
    __shared__ float sB0[32], sB1[32], sFB[32], sVB[32], sRB[3], sSB[1];

    const int v = blockIdx.x;
    const int t = threadIdx.x;
    const int c = min(count[v], CAP);
    if (c == 0) return;

    // ---- phase 1: async DMA of packed fp32 weights into LDS scratch ----
#if USE_DMA
    {
        // w0: 8064 B = 7 x 1024 + 896
        const float* g = w0g + (size_t)v * 2016;
        #pragma unroll
        for (int k = 0; k < 7; k++) dma16(g + k * 256 + t * 4, scr + SCR_W0 + k * 256);
        if (t * 16 < 896) dma16(g + 7 * 256 + t * 4, scr + SCR_W0 + 7 * 256);
        // vw: 7552 B = 7 x 1024 + 384
        g = vwg + (size_t)v * 1888;
        #pragma unroll
        for (int k = 0; k < 7; k++) dma16(g + k * 256 + t * 4, scr + SCR_VW + k * 256);
        if (t * 16 < 384) dma16(g + 7 * 256 + t * 4, scr + SCR_VW + 7 * 256);
        // w1 / fw: 4096 B each
        g = w1g + (size_t)v * 1024;
        #pragma unroll
        for (int k = 0; k < 4; k++) dma16(g + k * 256 + t * 4, scr + SCR_W1 + k * 256);
        g = fwg + (size_t)v * 1024;
        #pragma unroll
        for (int k = 0; k < 4; k++) dma16(g + k * 256 + t * 4, scr + SCR_FW + k * 256);
        // sw: 128 B, rw: 384 B
        if (t * 16 < 128) dma16(swg + (size_t)v * 32 + t * 4, scr + SCR_SW);
        if (t * 16 < 384) dma16(rwg + (size_t)v * 96 + t * 4, scr + SCR_RW);
    }
#endif
    // biases via normal loads (few; overlap with DMA drain)
    if (t < 32) {
        sB0[t] = b0g[v * 32 + t];
        sB1[t] = b1g[v * 32 + t];
        sFB[t] = fbg[v * 32 + t];
        sVB[t] = vbg[v * 32 + t];
    }
    if (t < 3) sRB[t] = rbg[v * 3 + t];
    if (t == 3) sSB[0] = sbg[v];

    // prefetch first iteration's point data (overlaps DMA drain)
    float pxc, pyc, pzc, dxc, dyc, dzc;
    int nc;
    {
        int sl = min(t >> 1, c - 1);
        nc = plist[v * CAP + sl];
        pxc = pts[3 * nc]; pyc = pts[3 * nc + 1]; pzc = pts[3 * nc + 2];
        int ray = nc >> 7;
        dxc = vds[3 * ray]; dyc = vds[3 * ray + 1]; dzc = vds[3 * ray + 2];
    }

    __syncthreads();   // drains DMA (vmcnt) + bias ds_writes

    // ---- phase 2: LDS->LDS repack fp32 -> skewed fp16 ----
    {
#if USE_DMA
        const float* w0p = scr + SCR_W0;
        const float* vwp = scr + SCR_VW;
        const float* w1p = scr + SCR_W1;
        const float* fwp = scr + SCR_FW;
        const float* swp = scr + SCR_SW;
        const float* rwp = scr + SCR_RW;
#else
        const float* w0p = w0g + (size_t)v * 2016;
        const float* vwp = vwg + (size_t)v * 1888;
        const float* w1p = w1g + (size_t)v * 1024;
        const float* fwp = fwg + (size_t)v * 1024;
        const float* swp = swg + (size_t)v * 32;
        const float* rwp = rwg + (size_t)v * 96;
#endif
        #pragma unroll
        for (int i = t; i < 1024; i += 64) {
            int r = i >> 5, j = i & 31;
            const float* rp = w0p + r * 63;
            float f0 = rp[2 * j];
            float f1 = (j < 31) ? rp[2 * j + 1] : 0.f;
            sW0[(r >> 4) * W0_HALF + (r & 15) * 32 + j] = pk(f0, f1);
        }
        #pragma unroll
        for (int i = t; i < 1024; i += 64) {
            int r = i >> 5, j = i & 31;
            const float* rp = vwp + r * 59;
            float f0 = (j < 30) ? rp[2 * j] : 0.f;
            float f1 = (j < 29) ? rp[2 * j + 1] : 0.f;
            sVW[(r >> 4) * W0_HALF + (r & 15) * 32 + j] = pk(f0, f1);
        }
        #pragma unroll
        for (int k = t; k < 256; k += 64) {
            float4 f = ((const float4*)w1p)[k];
            int r = k >> 3, jj = (k & 7) * 2;
            h2* dst = &sW1[(r >> 4) * W1_HALF + (r & 15) * 16 + jj];
            dst[0] = pk(f.x, f.y); dst[1] = pk(f.z, f.w);
        }
        #pragma unroll
        for (int k = t; k < 256; k += 64) {
            float4 f = ((const float4*)fwp)[k];
            int r = k >> 3, jj = (k & 7) * 2;
            h2* dst = &sFW[(r >> 4) * W1_HALF + (r & 15) * 16 + jj];
            dst[0] = pk(f.x, f.y); dst[1] = pk(f.z, f.w);
        }
        if (t < 8) {
            float4 f = ((const float4*)swp)[t];
            sSW[2 * t] = pk(f.x, f.y); sSW[2 * t + 1] = pk(f.z, f.w);
        }
        if (t < 24) {
            float4 f = ((const float4*)rwp)[t];
            h2* dst = &sRW[(t >> 3) * 16 + (t & 7) * 2];
            dst[0] = pk(f.x, f.y); dst[1] = pk(f.z, f.w);
        }
    }
    __syncthreads();

    const int half = t & 1;          // 2 lanes per point: 16 rows each
    const int rb16 = half << 4;

    for (int base = 0; base < c; base += 32) {
        const int slot = base + (t >> 1);
        const bool active = slot < c;
        const int n = nc;
        const float px = pxc, py = pyc, pz = pzc;
        const float dx = dxc, dy = dyc, dz = dzc;

        // prefetch next iteration's gather (hides plist->pts chain)
        if (base + 32 < c) {
            int sl2 = min(base + 32 + (t >> 1), c - 1);
            nc = plist[v * CAP + sl2];
            pxc = pts[3 * nc]; pyc = pts[3 * nc + 1]; pzc = pts[3 * nc + 2];
            int ray2 = nc >> 7;
            dxc = vds[3 * ray2]; dyc = vds[3 * ray2 + 1]; dzc = vds[3 * ray2 + 2];
        }

        // ---- xyz encoding packed directly into h2 (carry chain) ----
        h2 eph[32];
        eph[0] = pk(px, py);
        {
            float carry = pz, f = 1.f;
            #pragma unroll
            for (int k = 0; k < 10; k++) {
                float s0 = __sinf(px * f), s1 = __sinf(py * f), s2 = __sinf(pz * f);
                float c0 = __cosf(px * f), c1 = __cosf(py * f), c2 = __cosf(pz * f);
                eph[1 + 3 * k] = pk(carry, s0);
                eph[2 + 3 * k] = pk(s1, s2);
                eph[3 + 3 * k] = pk(c0, c1);
                carry = c2;
                f *= 2.f;
            }
            eph[31] = pk(carry, 0.f);
        }

        // ---- layer 0 ----
        float h[16];
        #pragma unroll
        for (int o = 0; o < 16; o++) {
            const h2* wr = &sW0[half * W0_HALF + o * 32];
            float a0 = sB0[rb16 + o], a1 = 0.f;
            #pragma unroll
            for (int j = 0; j < 32; j += 2) {
                a0 = FDOT2(wr[j], eph[j], a0);
                a1 = FDOT2(wr[j + 1], eph[j + 1], a1);
            }
            h[o] = fmaxf(a0 + a1, 0.f);
        }
        h2 hh[16];
        {
            float ho[16];
            #pragma unroll
            for (int j = 0; j < 16; j++) ho[j] = __shfl_xor(h[j], 1, 64);
            #pragma unroll
            for (int j = 0; j < 8; j++) {
                hh[j]     = pk(half ? ho[2 * j] : h[2 * j],  half ? ho[2 * j + 1] : h[2 * j + 1]);
                hh[8 + j] = pk(half ? h[2 * j] : ho[2 * j],  half ? h[2 * j + 1] : ho[2 * j + 1]);
            }
        }

        // ---- layer 1 ----
        float g[16];
        #pragma unroll
        for (int o = 0; o < 16; o++) {
            const h2* wr = &sW1[half * W1_HALF + o * 16];
            float a0 = sB1[rb16 + o], a1 = 0.f;
            #pragma unroll
            for (int j = 0; j < 16; j += 2) {
                a0 = FDOT2(wr[j], hh[j], a0);
                a1 = FDOT2(wr[j + 1], hh[j + 1], a1);
            }
            g[o] = fmaxf(a0 + a1, 0.f);
        }
        h2 gh[16];
        {
            float go[16];
            #pragma unroll
            for (int j = 0; j < 16; j++) go[j] = __shfl_xor(g[j], 1, 64);
            #pragma unroll
            for (int j = 0; j < 8; j++) {
                gh[j]     = pk(half ? go[2 * j] : g[2 * j],  half ? go[2 * j + 1] : g[2 * j + 1]);
                gh[8 + j] = pk(half ? g[2 * j] : go[2 * j],  half ? g[2 * j + 1] : go[2 * j + 1]);
            }
        }

        // ---- sigma ----
        float sg;
        {
            float a0 = sSB[0], a1 = 0.f;
            #pragma unroll
            for (int j = 0; j < 16; j += 2) {
                a0 = FDOT2(sSW[j], gh[j], a0);
                a1 = FDOT2(sSW[j + 1], gh[j + 1], a1);
            }
            sg = a0 + a1;
        }

        // ---- feature layer (no relu) ----
        float ft[16];
        #pragma unroll
        for (int o = 0; o < 16; o++) {
            const h2* wr = &sFW[half * W1_HALF + o * 16];
            float a0 = sFB[rb16 + o], a1 = 0.f;
            #pragma unroll
            for (int j = 0; j < 16; j += 2) {
                a0 = FDOT2(wr[j], gh[j], a0);
                a1 = FDOT2(wr[j + 1], gh[j + 1], a1);
            }
            ft[o] = a0 + a1;
        }

        // ---- view input: feat(32) + dir encoding(27) + pad ----
        h2 hv[32];
        {
            float fo[16];
            #pragma unroll
            for (int j = 0; j < 16; j++) fo[j] = __shfl_xor(ft[j], 1, 64);
            #pragma unroll
            for (int j = 0; j < 8; j++) {
                hv[j]     = pk(half ? fo[2 * j] : ft[2 * j],  half ? fo[2 * j + 1] : ft[2 * j + 1]);
                hv[8 + j] = pk(half ? ft[2 * j] : fo[2 * j],  half ? ft[2 * j + 1] : fo[2 * j + 1]);
            }
            hv[16] = pk(dx, dy);
            float carry = dz, f = 1.f;
            #pragma unroll
            for (int k = 0; k < 4; k++) {
                float s0 = __sinf(dx * f), s1 = __sinf(dy * f), s2 = __sinf(dz * f);
                float c0 = __cosf(dx * f), c1 = __cosf(dy * f), c2 = __cosf(dz * f);
                hv[17 + 3 * k] = pk(carry, s0);
                hv[18 + 3 * k] = pk(s1, s2);
                hv[19 + 3 * k] = pk(c0, c1);
                carry = c2;
                f *= 2.f;
            }
            hv[29] = pk(carry, 0.f);
            hv[30] = pk(0.f, 0.f);
            hv[31] = pk(0.f, 0.f);
        }

        // ---- view layer ----
        float h3[16];
        #pragma unroll
        for (int o = 0; o < 16; o++) {
            const h2* wr = &sVW[half * W0_HALF + o * 32];
            float a0 = sVB[rb16 + o], a1 = 0.f;
            #pragma unroll
            for (int j = 0; j < 32; j += 2) {
                a0 = FDOT2(wr[j], hv[j], a0);
                a1 = FDOT2(wr[j + 1], hv[j + 1], a1);
            }
            h3[o] = fmaxf(a0 + a1, 0.f);
        }
        h2 h3h[16];
        {
            float ho[16];
            #pragma unroll
            for (int j = 0; j < 16; j++) ho[j] = __shfl_xor(h3[j], 1, 64);
            #pragma unroll
            for (int j = 0; j < 8; j++) {
                h3h[j]     = pk(half ? ho[2 * j] : h3[2 * j],  half ? ho[2 * j + 1] : h3[2 * j + 1]);
                h3h[8 + j] = pk(half ? h3[2 * j] : ho[2 * j],  half ? h3[2 * j + 1] : ho[2 * j + 1]);
            }
        }

        // ---- rgb ----
        float r0 = sRB[0], r1 = sRB[1], r2 = sRB[2];
        {
            float b0 = 0.f, b1 = 0.f, b2 = 0.f;
            #pragma unroll
            for (int j = 0; j < 16; j += 2) {
                r0 = FDOT2(sRW[j], h3h[j], r0);       b0 = FDOT2(sRW[j + 1], h3h[j + 1], b0);
                r1 = FDOT2(sRW[16 + j], h3h[j], r1);  b1 = FDOT2(sRW[16 + j + 1], h3h[j + 1], b1);
                r2 = FDOT2(sRW[32 + j], h3h[j], r2);  b2 = FDOT2(sRW[32 + j + 1], h3h[j + 1], b2);
            }
            r0 += b0; r1 += b1; r2 += b2;
        }

        if (active && half == 0) {
            out[3 * n + 0] = r0;
            out[3 * n + 1] = r1;
            out[3 * n + 2] = r2;
            out[3 * NPTS + n] = sg;
        }
    }
}

extern "C" void kernel_launch(void* const* d_in, const int* in_sizes, int n_in,
                              void* d_out, int out_size, void* d_ws, size_t ws_size,
                              hipStream_t stream) {
    const float* pts = (const float*)d_in[0];
    const float* vds = (const float*)d_in[1];
    const float* w0  = (const float*)d_in[2];
    const float* b0  = (const float*)d_in[3];
    const float* w1  = (const float*)d_in[4];
    const float* b1  = (const float*)d_in[5];
    const float* fw  = (const float*)d_in[6];
    const float* fb  = (const float*)d_in[7];
    const float* sw  = (const float*)d_in[8];
    const float* sb  = (const float*)d_in[9];
    const float* vw  = (const float*)d_in[10];
    const float* vb  = (const float*)d_in[11];
    const float* rw  = (const float*)d_in[12];
    const float* rb  = (const float*)d_in[13];
    float* out = (float*)d_out;

    int* count = (int*)d_ws;
    int* plist = (int*)((char*)d_ws + NM * sizeof(int));

    (void)hipMemsetAsync(count, 0, NM * sizeof(int), stream);
    k_bucket<<<NPTS / 256, 256, 0, stream>>>(pts, count, plist);
    k_mlp<<<NM, 64, 0, stream>>>(pts, vds, w0, b0, w1, b1, fw, fb, sw, sb,
                                 vw, vb, rw, rb, count, plist, out);
}